// Round 3
// baseline (141.574 us; speedup 1.0000x reference)
//
#include <hip/hip_runtime.h>
#include <hip/hip_bf16.h>
#include <stdint.h>

#define N_PTS 4096
#define DIM 512
#define MARGIN_F 0.3f
#define POS_INF_BITS 0x7f800000

typedef short bf16x8 __attribute__((ext_vector_type(8)));
typedef float f32x4 __attribute__((ext_vector_type(4)));

__device__ __forceinline__ unsigned short f2bf(float f) {
    unsigned int b = __float_as_uint(f);
    b += 0x7FFF + ((b >> 16) & 1);   // round-to-nearest-even
    return (unsigned short)(b >> 16);
}

// async global->LDS, 16B per lane; LDS dest is wave-uniform base + lane*16
__device__ __forceinline__ void async16(const unsigned short* g, unsigned short* l) {
    __builtin_amdgcn_global_load_lds(
        (const __attribute__((address_space(1))) unsigned int*)g,
        (__attribute__((address_space(3))) unsigned int*)l,
        16, 0, 0);
}

// One wave per row: bf16 copy + exact fp32 norms + init ap/an + zero done-counter.
__global__ __launch_bounds__(256) void prep_kernel(
    const float* __restrict__ src, const float* __restrict__ tgt,
    unsigned short* __restrict__ src_bf, unsigned short* __restrict__ tgt_bf,
    float* __restrict__ e1, float* __restrict__ e2,
    float* __restrict__ ap, float* __restrict__ an,
    int* __restrict__ done_ctr)
{
    const int row  = blockIdx.x * 4 + (threadIdx.x >> 6);
    const int lane = threadIdx.x & 63;

    if (blockIdx.x == 0 && threadIdx.x == 0) *done_ctr = 0;

    const float4* s4 = (const float4*)(src + (size_t)row * DIM);
    const float4* t4 = (const float4*)(tgt + (size_t)row * DIM);
    float4 a0 = s4[lane], a1 = s4[lane + 64];
    float4 b0 = t4[lane], b1 = t4[lane + 64];

    ushort4 u;
    ushort4* so = (ushort4*)(src_bf + (size_t)row * DIM);
    ushort4* to = (ushort4*)(tgt_bf + (size_t)row * DIM);
    u.x = f2bf(a0.x); u.y = f2bf(a0.y); u.z = f2bf(a0.z); u.w = f2bf(a0.w); so[lane] = u;
    u.x = f2bf(a1.x); u.y = f2bf(a1.y); u.z = f2bf(a1.z); u.w = f2bf(a1.w); so[lane + 64] = u;
    u.x = f2bf(b0.x); u.y = f2bf(b0.y); u.z = f2bf(b0.z); u.w = f2bf(b0.w); to[lane] = u;
    u.x = f2bf(b1.x); u.y = f2bf(b1.y); u.z = f2bf(b1.z); u.w = f2bf(b1.w); to[lane + 64] = u;

    float s1 = a0.x*a0.x + a0.y*a0.y + a0.z*a0.z + a0.w*a0.w
             + a1.x*a1.x + a1.y*a1.y + a1.z*a1.z + a1.w*a1.w;
    float s2 = b0.x*b0.x + b0.y*b0.y + b0.z*b0.z + b0.w*b0.w
             + b1.x*b1.x + b1.y*b1.y + b1.z*b1.z + b1.w*b1.w;
    for (int off = 32; off; off >>= 1) {
        s1 += __shfl_down(s1, off);
        s2 += __shfl_down(s2, off);
    }
    if (lane == 0) {
        e1[row] = s1;
        e2[row] = s2;
        ap[row] = 0.0f;
        an[row] = __int_as_float(POS_INF_BITS);
    }
}

#define BM 128
#define BN 128
#define BK 64
#define NBLK 1024   // (N/BM)*(N/BN)

__global__ __launch_bounds__(256, 4) void dist_kernel(
    const unsigned short* __restrict__ src_bf,
    const unsigned short* __restrict__ tgt_bf,
    const float* __restrict__ e1, const float* __restrict__ e2,
    const int* __restrict__ labels,
    float* __restrict__ ap, float* __restrict__ an,
    int* __restrict__ done_ctr, float* __restrict__ out)
{
    // [128][64] bf16, XOR-swizzled at 16B-chunk granularity:
    // physical chunk col = logical col ^ (row & 7). Swizzle is applied on the
    // GLOBAL source address (per-lane free) since global_load_lds's LDS dest
    // is fixed at base+lane*16. Makes ds_read_b128 perfectly bank-balanced.
    __shared__ unsigned short As[BM * BK];
    __shared__ unsigned short Bs[BN * BK];
    __shared__ int   li[BM];
    __shared__ int   lj[BN];
    __shared__ float e1s[BM];
    __shared__ float e2s[BN];
    __shared__ int   is_last;

    const int i0 = blockIdx.y * BM;
    const int j0 = blockIdx.x * BN;
    const int t = threadIdx.x;
    const int lane = t & 63;
    const int wave = t >> 6;

    if (t < BM) { li[t] = labels[i0 + t]; e1s[t] = e1[i0 + t]; }
    else        { int u = t - BM; lj[u] = labels[j0 + u]; e2s[u] = e2[j0 + u]; }

    // staging: 1024 16B-chunks per matrix per K-tile; thread t covers group g
    // chunk c = g*256 + t -> row = g*32 + (t>>3), physical col chunk = t&7,
    // which must hold logical chunk (t&7)^(row&7)  -> gather from global.
    const int srow = t >> 3;                       // 0..31
    const int scol = ((t & 7) ^ (srow & 7)) * 8;   // swizzled source col (elems)
    const unsigned short* gA = src_bf + (size_t)(i0 + srow) * DIM + scol;
    const unsigned short* gB = tgt_bf + (size_t)(j0 + srow) * DIM + scol;
    unsigned short* ldsA = &As[0] + wave * 512;    // + g*2048 per group
    unsigned short* ldsB = &Bs[0] + wave * 512;

    // wave -> 64x64 subtile: 4x4 of 16x16x32 MFMA
    const int wm = (wave >> 1) * 64;
    const int wn = (wave & 1) * 64;
    const int fr = lane & 15;
    const int quad = lane >> 4;
    const int fsw = fr & 7;                        // read-side XOR key

    f32x4 acc[4][4];
    #pragma unroll
    for (int a = 0; a < 4; a++)
        #pragma unroll
        for (int b = 0; b < 4; b++)
            acc[a][b] = (f32x4){0.f, 0.f, 0.f, 0.f};

    for (int kk = 0; kk < DIM; kk += BK) {
        __syncthreads();
        #pragma unroll
        for (int g = 0; g < 4; g++) {
            async16(gA + (size_t)g * 32 * DIM + kk, ldsA + g * 2048);
            async16(gB + (size_t)g * 32 * DIM + kk, ldsB + g * 2048);
        }
        __syncthreads();   // vmcnt(0) drain inserted by compiler

        #pragma unroll
        for (int s = 0; s < 2; s++) {
            bf16x8 af[4], bf[4];
            #pragma unroll
            for (int x = 0; x < 4; x++) {
                const int ar = wm + x * 16 + fr;
                const int br = wn + x * 16 + fr;
                const int cp = ((s << 2) | quad) ^ fsw;   // physical chunk
                af[x] = *(const bf16x8*)&As[ar * BK + cp * 8];
                bf[x] = *(const bf16x8*)&Bs[br * BK + cp * 8];
            }
            #pragma unroll
            for (int tm = 0; tm < 4; tm++)
                #pragma unroll
                for (int tn = 0; tn < 4; tn++)
                    acc[tm][tn] = __builtin_amdgcn_mfma_f32_16x16x32_bf16(
                        af[tm], bf[tn], acc[tm][tn], 0, 0, 0);
        }
    }

    // epilogue: dist -> masked row max/min -> 16-lane reduce -> atomics
    const float INF = __int_as_float(POS_INF_BITS);
    #pragma unroll
    for (int tm = 0; tm < 4; tm++) {
        #pragma unroll
        for (int r = 0; r < 4; r++) {
            const int rl = wm + tm * 16 + quad * 4 + r;  // local row
            const float e1v = e1s[rl];
            const int   liv = li[rl];
            float apv = 0.0f;   // neutral for max (dist >= 0, global init 0)
            float anv = INF;
            #pragma unroll
            for (int tn = 0; tn < 4; tn++) {
                const int cl = wn + tn * 16 + fr;        // local col
                float d = e1v + e2s[cl] - 2.0f * acc[tm][tn][r];
                d = fmaxf(d, 0.0f);
                if (liv == lj[cl]) apv = fmaxf(apv, d);
                else               anv = fminf(anv, d);
            }
            #pragma unroll
            for (int off = 1; off < 16; off <<= 1) {
                apv = fmaxf(apv, __shfl_xor(apv, off));
                anv = fminf(anv, __shfl_xor(anv, off));
            }
            if (fr == 0) {
                // non-negative floats: int compare == float compare
                atomicMax((int*)&ap[i0 + rl], __float_as_int(apv));
                atomicMin((int*)&an[i0 + rl], __float_as_int(anv));
            }
        }
    }

    // fused loss: last block to finish reduces ap/an -> scalar
    __syncthreads();
    if (t == 0) {
        __threadfence();
        int old = __hip_atomic_fetch_add(done_ctr, 1, __ATOMIC_ACQ_REL,
                                         __HIP_MEMORY_SCOPE_AGENT);
        is_last = (old == NBLK - 1);
    }
    __syncthreads();
    if (is_last) {
        __threadfence();
        float s = 0.0f;
        for (int i = t; i < N_PTS; i += 256) {
            int ai = __hip_atomic_load((int*)&ap[i], __ATOMIC_RELAXED,
                                       __HIP_MEMORY_SCOPE_AGENT);
            int ni = __hip_atomic_load((int*)&an[i], __ATOMIC_RELAXED,
                                       __HIP_MEMORY_SCOPE_AGENT);
            float v = __int_as_float(ai) - __int_as_float(ni) + MARGIN_F;
            s += fmaxf(v, 0.0f);
        }
        for (int off = 32; off; off >>= 1) s += __shfl_down(s, off);
        __shared__ float red[4];
        if ((t & 63) == 0) red[t >> 6] = s;
        __syncthreads();
        if (t == 0) out[0] = (red[0] + red[1] + red[2] + red[3]) / (float)N_PTS;
    }
}

extern "C" void kernel_launch(void* const* d_in, const int* in_sizes, int n_in,
                              void* d_out, int out_size, void* d_ws, size_t ws_size,
                              hipStream_t stream) {
    const float* src   = (const float*)d_in[0];
    const float* tgt   = (const float*)d_in[1];
    const int* labels  = (const int*)d_in[2];

    char* ws = (char*)d_ws;
    const size_t featB = (size_t)N_PTS * DIM * sizeof(unsigned short);  // 4 MiB
    unsigned short* src_bf = (unsigned short*)ws;
    unsigned short* tgt_bf = (unsigned short*)(ws + featB);
    float* e1 = (float*)(ws + 2 * featB);
    float* e2 = e1 + N_PTS;
    float* ap = e2 + N_PTS;
    float* an = ap + N_PTS;
    int* done_ctr = (int*)(an + N_PTS);

    prep_kernel<<<N_PTS / 4, 256, 0, stream>>>(src, tgt, src_bf, tgt_bf,
                                               e1, e2, ap, an, done_ctr);
    dim3 grid(N_PTS / BN, N_PTS / BM);
    dist_kernel<<<grid, 256, 0, stream>>>(src_bf, tgt_bf, e1, e2, labels,
                                          ap, an, done_ctr, (float*)d_out);
}

// Round 4
// 132.022 us; speedup vs baseline: 1.0724x; 1.0724x over previous
//
#include <hip/hip_runtime.h>
#include <hip/hip_bf16.h>
#include <stdint.h>

#define N_PTS 4096
#define DIM 512
#define MARGIN_F 0.3f
#define POS_INF_BITS 0x7f800000

typedef short bf16x8 __attribute__((ext_vector_type(8)));
typedef float f32x4 __attribute__((ext_vector_type(4)));

__device__ __forceinline__ unsigned short f2bf(float f) {
    unsigned int b = __float_as_uint(f);
    b += 0x7FFF + ((b >> 16) & 1);   // round-to-nearest-even
    return (unsigned short)(b >> 16);
}

// async global->LDS, 16B per lane; LDS dest is wave-uniform base + lane*16
__device__ __forceinline__ void async16(const unsigned short* g, unsigned short* l) {
    __builtin_amdgcn_global_load_lds(
        (const __attribute__((address_space(1))) unsigned int*)g,
        (__attribute__((address_space(3))) unsigned int*)l,
        16, 0, 0);
}

// One wave per row: bf16 copy + exact fp32 norms + init ap/an + zero done-counter.
__global__ __launch_bounds__(256) void prep_kernel(
    const float* __restrict__ src, const float* __restrict__ tgt,
    unsigned short* __restrict__ src_bf, unsigned short* __restrict__ tgt_bf,
    float* __restrict__ e1, float* __restrict__ e2,
    float* __restrict__ ap, float* __restrict__ an,
    int* __restrict__ done_ctr)
{
    const int row  = blockIdx.x * 4 + (threadIdx.x >> 6);
    const int lane = threadIdx.x & 63;

    if (blockIdx.x == 0 && threadIdx.x == 0) *done_ctr = 0;

    const float4* s4 = (const float4*)(src + (size_t)row * DIM);
    const float4* t4 = (const float4*)(tgt + (size_t)row * DIM);
    float4 a0 = s4[lane], a1 = s4[lane + 64];
    float4 b0 = t4[lane], b1 = t4[lane + 64];

    ushort4 u;
    ushort4* so = (ushort4*)(src_bf + (size_t)row * DIM);
    ushort4* to = (ushort4*)(tgt_bf + (size_t)row * DIM);
    u.x = f2bf(a0.x); u.y = f2bf(a0.y); u.z = f2bf(a0.z); u.w = f2bf(a0.w); so[lane] = u;
    u.x = f2bf(a1.x); u.y = f2bf(a1.y); u.z = f2bf(a1.z); u.w = f2bf(a1.w); so[lane + 64] = u;
    u.x = f2bf(b0.x); u.y = f2bf(b0.y); u.z = f2bf(b0.z); u.w = f2bf(b0.w); to[lane] = u;
    u.x = f2bf(b1.x); u.y = f2bf(b1.y); u.z = f2bf(b1.z); u.w = f2bf(b1.w); to[lane + 64] = u;

    float s1 = a0.x*a0.x + a0.y*a0.y + a0.z*a0.z + a0.w*a0.w
             + a1.x*a1.x + a1.y*a1.y + a1.z*a1.z + a1.w*a1.w;
    float s2 = b0.x*b0.x + b0.y*b0.y + b0.z*b0.z + b0.w*b0.w
             + b1.x*b1.x + b1.y*b1.y + b1.z*b1.z + b1.w*b1.w;
    for (int off = 32; off; off >>= 1) {
        s1 += __shfl_down(s1, off);
        s2 += __shfl_down(s2, off);
    }
    if (lane == 0) {
        e1[row] = s1;
        e2[row] = s2;
        ap[row] = 0.0f;
        an[row] = __int_as_float(POS_INF_BITS);
    }
}

#define BM 128
#define BN 128
#define BK 32
#define NBLK 1024   // (N/BM)*(N/BN)

__global__ __launch_bounds__(256) void dist_kernel(
    const unsigned short* __restrict__ src_bf,
    const unsigned short* __restrict__ tgt_bf,
    const float* __restrict__ e1, const float* __restrict__ e2,
    const int* __restrict__ labels,
    float* __restrict__ ap, float* __restrict__ an,
    int* __restrict__ done_ctr, float* __restrict__ out)
{
    // [128][32] bf16, XOR-swizzled at 16B-chunk granularity:
    // physical chunk = logical chunk ^ ((row>>1)&3). Applied on the GLOBAL
    // source address (global_load_lds LDS dest is fixed base+lane*16).
    // Start-bank = 16*(row&1) + 4*(quad^((row>>1)&3)) -> all 8 multiple-of-4
    // start banks x2 lanes per 16-lane group: balanced at every phasing
    // granularity (BK=64 version measured 0 conflicts; this keeps that
    // property at 16 KB LDS instead of 32 KB).
    __shared__ unsigned short As[BM * BK];
    __shared__ unsigned short Bs[BN * BK];
    __shared__ int   li[BM];
    __shared__ int   lj[BN];
    __shared__ float e1s[BM];
    __shared__ float e2s[BN];
    __shared__ int   is_last;

    const int i0 = blockIdx.y * BM;
    const int j0 = blockIdx.x * BN;
    const int t = threadIdx.x;
    const int lane = t & 63;
    const int wave = t >> 6;

    if (t < BM) { li[t] = labels[i0 + t]; e1s[t] = e1[i0 + t]; }
    else        { int u = t - BM; lj[u] = labels[j0 + u]; e2s[u] = e2[j0 + u]; }

    // staging: 512 16B-chunks per matrix per K-tile; thread t covers chunks
    // t (rows 0..63) and t+256 (rows 64..127). Physical chunk col = t&3 holds
    // logical chunk (t&3) ^ ((row>>1)&3); key identical for row and row+64.
    const int srow = t >> 2;                              // 0..63
    const int scol = ((t & 3) ^ ((srow >> 1) & 3)) * 8;   // swizzled source col
    const unsigned short* gA0 = src_bf + (size_t)(i0 + srow) * DIM + scol;
    const unsigned short* gA1 = src_bf + (size_t)(i0 + 64 + srow) * DIM + scol;
    const unsigned short* gB0 = tgt_bf + (size_t)(j0 + srow) * DIM + scol;
    const unsigned short* gB1 = tgt_bf + (size_t)(j0 + 64 + srow) * DIM + scol;
    unsigned short* ldsA0 = &As[0] + wave * 512;          // chunk base wave*64
    unsigned short* ldsA1 = &As[0] + 2048 + wave * 512;   // chunk base 256+wave*64
    unsigned short* ldsB0 = &Bs[0] + wave * 512;
    unsigned short* ldsB1 = &Bs[0] + 2048 + wave * 512;

    // wave -> 64x64 subtile: 4x4 of 16x16x32 MFMA
    const int wm = (wave >> 1) * 64;
    const int wn = (wave & 1) * 64;
    const int fr = lane & 15;
    const int quad = lane >> 4;
    const int fkey = (fr >> 1) & 3;                       // read-side XOR key

    f32x4 acc[4][4];
    #pragma unroll
    for (int a = 0; a < 4; a++)
        #pragma unroll
        for (int b = 0; b < 4; b++)
            acc[a][b] = (f32x4){0.f, 0.f, 0.f, 0.f};

    for (int kk = 0; kk < DIM; kk += BK) {
        __syncthreads();
        async16(gA0 + kk, ldsA0);
        async16(gA1 + kk, ldsA1);
        async16(gB0 + kk, ldsB0);
        async16(gB1 + kk, ldsB1);
        __syncthreads();   // vmcnt(0) drain inserted by compiler

        bf16x8 af[4], bf[4];
        const int cp = (quad ^ fkey) * 8;                 // physical chunk off
        #pragma unroll
        for (int x = 0; x < 4; x++) {
            af[x] = *(const bf16x8*)&As[(wm + x * 16 + fr) * BK + cp];
            bf[x] = *(const bf16x8*)&Bs[(wn + x * 16 + fr) * BK + cp];
        }
        #pragma unroll
        for (int tm = 0; tm < 4; tm++)
            #pragma unroll
            for (int tn = 0; tn < 4; tn++)
                acc[tm][tn] = __builtin_amdgcn_mfma_f32_16x16x32_bf16(
                    af[tm], bf[tn], acc[tm][tn], 0, 0, 0);
    }

    // epilogue: dist -> masked row max/min -> 16-lane reduce -> atomics
    const float INF = __int_as_float(POS_INF_BITS);
    #pragma unroll
    for (int tm = 0; tm < 4; tm++) {
        #pragma unroll
        for (int r = 0; r < 4; r++) {
            const int rl = wm + tm * 16 + quad * 4 + r;  // local row
            const float e1v = e1s[rl];
            const int   liv = li[rl];
            float apv = 0.0f;   // neutral for max (dist >= 0, global init 0)
            float anv = INF;
            #pragma unroll
            for (int tn = 0; tn < 4; tn++) {
                const int cl = wn + tn * 16 + fr;        // local col
                float d = e1v + e2s[cl] - 2.0f * acc[tm][tn][r];
                d = fmaxf(d, 0.0f);
                if (liv == lj[cl]) apv = fmaxf(apv, d);
                else               anv = fminf(anv, d);
            }
            #pragma unroll
            for (int off = 1; off < 16; off <<= 1) {
                apv = fmaxf(apv, __shfl_xor(apv, off));
                anv = fminf(anv, __shfl_xor(anv, off));
            }
            if (fr == 0) {
                // non-negative floats: int compare == float compare
                atomicMax((int*)&ap[i0 + rl], __float_as_int(apv));
                atomicMin((int*)&an[i0 + rl], __float_as_int(anv));
            }
        }
    }

    // fused loss: last block to finish reduces ap/an -> scalar
    __syncthreads();
    if (t == 0) {
        __threadfence();
        int old = __hip_atomic_fetch_add(done_ctr, 1, __ATOMIC_ACQ_REL,
                                         __HIP_MEMORY_SCOPE_AGENT);
        is_last = (old == NBLK - 1);
    }
    __syncthreads();
    if (is_last) {
        __threadfence();
        float s = 0.0f;
        for (int i = t; i < N_PTS; i += 256) {
            int ai = __hip_atomic_load((int*)&ap[i], __ATOMIC_RELAXED,
                                       __HIP_MEMORY_SCOPE_AGENT);
            int ni = __hip_atomic_load((int*)&an[i], __ATOMIC_RELAXED,
                                       __HIP_MEMORY_SCOPE_AGENT);
            float v = __int_as_float(ai) - __int_as_float(ni) + MARGIN_F;
            s += fmaxf(v, 0.0f);
        }
        for (int off = 32; off; off >>= 1) s += __shfl_down(s, off);
        __shared__ float red[4];
        if ((t & 63) == 0) red[t >> 6] = s;
        __syncthreads();
        if (t == 0) out[0] = (red[0] + red[1] + red[2] + red[3]) / (float)N_PTS;
    }
}

extern "C" void kernel_launch(void* const* d_in, const int* in_sizes, int n_in,
                              void* d_out, int out_size, void* d_ws, size_t ws_size,
                              hipStream_t stream) {
    const float* src   = (const float*)d_in[0];
    const float* tgt   = (const float*)d_in[1];
    const int* labels  = (const int*)d_in[2];

    char* ws = (char*)d_ws;
    const size_t featB = (size_t)N_PTS * DIM * sizeof(unsigned short);  // 4 MiB
    unsigned short* src_bf = (unsigned short*)ws;
    unsigned short* tgt_bf = (unsigned short*)(ws + featB);
    float* e1 = (float*)(ws + 2 * featB);
    float* e2 = e1 + N_PTS;
    float* ap = e2 + N_PTS;
    float* an = ap + N_PTS;
    int* done_ctr = (int*)(an + N_PTS);

    prep_kernel<<<N_PTS / 4, 256, 0, stream>>>(src, tgt, src_bf, tgt_bf,
                                               e1, e2, ap, an, done_ctr);
    dim3 grid(N_PTS / BN, N_PTS / BM);
    dist_kernel<<<grid, 256, 0, stream>>>(src_bf, tgt_bf, e1, e2, labels,
                                          ap, an, done_ctr, (float*)d_out);
}

// Round 5
// 111.851 us; speedup vs baseline: 1.2657x; 1.1803x over previous
//
#include <hip/hip_runtime.h>
#include <hip/hip_bf16.h>
#include <stdint.h>

#define N_PTS 4096
#define DIM 512
#define MARGIN_F 0.3f
#define POS_INF_BITS 0x7f800000

typedef short bf16x8 __attribute__((ext_vector_type(8)));
typedef float f32x4 __attribute__((ext_vector_type(4)));

__device__ __forceinline__ unsigned short f2bf(float f) {
    unsigned int b = __float_as_uint(f);
    b += 0x7FFF + ((b >> 16) & 1);   // round-to-nearest-even
    return (unsigned short)(b >> 16);
}

// async global->LDS, 16B per lane; LDS dest is wave-uniform base + lane*16
__device__ __forceinline__ void async16(const unsigned short* g, unsigned short* l) {
    __builtin_amdgcn_global_load_lds(
        (const __attribute__((address_space(1))) unsigned int*)g,
        (__attribute__((address_space(3))) unsigned int*)l,
        16, 0, 0);
}

// One wave per row: bf16 copy + exact fp32 norms + init ap/an.
__global__ __launch_bounds__(256) void prep_kernel(
    const float* __restrict__ src, const float* __restrict__ tgt,
    unsigned short* __restrict__ src_bf, unsigned short* __restrict__ tgt_bf,
    float* __restrict__ e1, float* __restrict__ e2,
    float* __restrict__ ap, float* __restrict__ an)
{
    const int row  = blockIdx.x * 4 + (threadIdx.x >> 6);
    const int lane = threadIdx.x & 63;

    const float4* s4 = (const float4*)(src + (size_t)row * DIM);
    const float4* t4 = (const float4*)(tgt + (size_t)row * DIM);
    float4 a0 = s4[lane], a1 = s4[lane + 64];
    float4 b0 = t4[lane], b1 = t4[lane + 64];

    ushort4 u;
    ushort4* so = (ushort4*)(src_bf + (size_t)row * DIM);
    ushort4* to = (ushort4*)(tgt_bf + (size_t)row * DIM);
    u.x = f2bf(a0.x); u.y = f2bf(a0.y); u.z = f2bf(a0.z); u.w = f2bf(a0.w); so[lane] = u;
    u.x = f2bf(a1.x); u.y = f2bf(a1.y); u.z = f2bf(a1.z); u.w = f2bf(a1.w); so[lane + 64] = u;
    u.x = f2bf(b0.x); u.y = f2bf(b0.y); u.z = f2bf(b0.z); u.w = f2bf(b0.w); to[lane] = u;
    u.x = f2bf(b1.x); u.y = f2bf(b1.y); u.z = f2bf(b1.z); u.w = f2bf(b1.w); to[lane + 64] = u;

    float s1 = a0.x*a0.x + a0.y*a0.y + a0.z*a0.z + a0.w*a0.w
             + a1.x*a1.x + a1.y*a1.y + a1.z*a1.z + a1.w*a1.w;
    float s2 = b0.x*b0.x + b0.y*b0.y + b0.z*b0.z + b0.w*b0.w
             + b1.x*b1.x + b1.y*b1.y + b1.z*b1.z + b1.w*b1.w;
    for (int off = 32; off; off >>= 1) {
        s1 += __shfl_down(s1, off);
        s2 += __shfl_down(s2, off);
    }
    if (lane == 0) {
        e1[row] = s1;
        e2[row] = s2;
        ap[row] = 0.0f;
        an[row] = __int_as_float(POS_INF_BITS);
    }
}

#define BM 128
#define BN 128
#define BK 32

__global__ __launch_bounds__(256) void dist_kernel(
    const unsigned short* __restrict__ src_bf,
    const unsigned short* __restrict__ tgt_bf,
    const float* __restrict__ e1, const float* __restrict__ e2,
    const int* __restrict__ labels,
    float* __restrict__ ap, float* __restrict__ an)
{
    // [128][32] bf16, XOR-swizzled at 16B-chunk granularity:
    // physical chunk = logical chunk ^ ((row>>1)&3). Applied on the GLOBAL
    // source address (global_load_lds LDS dest is fixed base+lane*16).
    // Measured: SQ_LDS_BANK_CONFLICT == 0 with this layout (rounds 3-4).
    // NOTE (round-4 lesson): do NOT fuse a device-scope-fenced reduction
    // into this kernel — per-block agent-scope release forces L2 writeback,
    // evicting the L2-resident panels (+25 us, FETCH 2.3x).
    __shared__ unsigned short As[BM * BK];
    __shared__ unsigned short Bs[BN * BK];
    __shared__ int   li[BM];
    __shared__ int   lj[BN];
    __shared__ float e1s[BM];
    __shared__ float e2s[BN];

    const int i0 = blockIdx.y * BM;
    const int j0 = blockIdx.x * BN;
    const int t = threadIdx.x;
    const int lane = t & 63;
    const int wave = t >> 6;

    if (t < BM) { li[t] = labels[i0 + t]; e1s[t] = e1[i0 + t]; }
    else        { int u = t - BM; lj[u] = labels[j0 + u]; e2s[u] = e2[j0 + u]; }

    // staging: 512 16B-chunks per matrix per K-tile; thread t covers chunks
    // t (rows 0..63) and t+256 (rows 64..127). Physical chunk col = t&3 holds
    // logical chunk (t&3) ^ ((row>>1)&3); key identical for row and row+64.
    const int srow = t >> 2;                              // 0..63
    const int scol = ((t & 3) ^ ((srow >> 1) & 3)) * 8;   // swizzled source col
    const unsigned short* gA0 = src_bf + (size_t)(i0 + srow) * DIM + scol;
    const unsigned short* gA1 = src_bf + (size_t)(i0 + 64 + srow) * DIM + scol;
    const unsigned short* gB0 = tgt_bf + (size_t)(j0 + srow) * DIM + scol;
    const unsigned short* gB1 = tgt_bf + (size_t)(j0 + 64 + srow) * DIM + scol;
    unsigned short* ldsA0 = &As[0] + wave * 512;          // chunk base wave*64
    unsigned short* ldsA1 = &As[0] + 2048 + wave * 512;   // chunk base 256+wave*64
    unsigned short* ldsB0 = &Bs[0] + wave * 512;
    unsigned short* ldsB1 = &Bs[0] + 2048 + wave * 512;

    // wave -> 64x64 subtile: 4x4 of 16x16x32 MFMA
    const int wm = (wave >> 1) * 64;
    const int wn = (wave & 1) * 64;
    const int fr = lane & 15;
    const int quad = lane >> 4;
    const int fkey = (fr >> 1) & 3;                       // read-side XOR key

    f32x4 acc[4][4];
    #pragma unroll
    for (int a = 0; a < 4; a++)
        #pragma unroll
        for (int b = 0; b < 4; b++)
            acc[a][b] = (f32x4){0.f, 0.f, 0.f, 0.f};

    for (int kk = 0; kk < DIM; kk += BK) {
        __syncthreads();
        async16(gA0 + kk, ldsA0);
        async16(gA1 + kk, ldsA1);
        async16(gB0 + kk, ldsB0);
        async16(gB1 + kk, ldsB1);
        __syncthreads();   // vmcnt(0) drain inserted by compiler

        bf16x8 af[4], bf[4];
        const int cp = (quad ^ fkey) * 8;                 // physical chunk off
        #pragma unroll
        for (int x = 0; x < 4; x++) {
            af[x] = *(const bf16x8*)&As[(wm + x * 16 + fr) * BK + cp];
            bf[x] = *(const bf16x8*)&Bs[(wn + x * 16 + fr) * BK + cp];
        }
        #pragma unroll
        for (int tm = 0; tm < 4; tm++)
            #pragma unroll
            for (int tn = 0; tn < 4; tn++)
                acc[tm][tn] = __builtin_amdgcn_mfma_f32_16x16x32_bf16(
                    af[tm], bf[tn], acc[tm][tn], 0, 0, 0);
    }

    // epilogue: dist -> masked row max/min -> 16-lane reduce -> atomics
    const float INF = __int_as_float(POS_INF_BITS);
    #pragma unroll
    for (int tm = 0; tm < 4; tm++) {
        #pragma unroll
        for (int r = 0; r < 4; r++) {
            const int rl = wm + tm * 16 + quad * 4 + r;  // local row
            const float e1v = e1s[rl];
            const int   liv = li[rl];
            float apv = 0.0f;   // neutral for max (dist >= 0, global init 0)
            float anv = INF;
            #pragma unroll
            for (int tn = 0; tn < 4; tn++) {
                const int cl = wn + tn * 16 + fr;        // local col
                float d = e1v + e2s[cl] - 2.0f * acc[tm][tn][r];
                d = fmaxf(d, 0.0f);
                if (liv == lj[cl]) apv = fmaxf(apv, d);
                else               anv = fminf(anv, d);
            }
            #pragma unroll
            for (int off = 1; off < 16; off <<= 1) {
                apv = fmaxf(apv, __shfl_xor(apv, off));
                anv = fminf(anv, __shfl_xor(anv, off));
            }
            if (fr == 0) {
                // non-negative floats: int compare == float compare
                atomicMax((int*)&ap[i0 + rl], __float_as_int(apv));
                atomicMin((int*)&an[i0 + rl], __float_as_int(anv));
            }
        }
    }
}

__global__ __launch_bounds__(256) void loss_kernel(
    const float* __restrict__ ap, const float* __restrict__ an,
    float* __restrict__ out)
{
    const int t = threadIdx.x;
    float s = 0.0f;
    for (int i = t; i < N_PTS; i += 256) {
        float v = ap[i] - an[i] + MARGIN_F;
        s += fmaxf(v, 0.0f);
    }
    for (int off = 32; off; off >>= 1) s += __shfl_down(s, off);
    __shared__ float red[4];
    if ((t & 63) == 0) red[t >> 6] = s;
    __syncthreads();
    if (t == 0) out[0] = (red[0] + red[1] + red[2] + red[3]) / (float)N_PTS;
}

extern "C" void kernel_launch(void* const* d_in, const int* in_sizes, int n_in,
                              void* d_out, int out_size, void* d_ws, size_t ws_size,
                              hipStream_t stream) {
    const float* src   = (const float*)d_in[0];
    const float* tgt   = (const float*)d_in[1];
    const int* labels  = (const int*)d_in[2];

    char* ws = (char*)d_ws;
    const size_t featB = (size_t)N_PTS * DIM * sizeof(unsigned short);  // 4 MiB
    unsigned short* src_bf = (unsigned short*)ws;
    unsigned short* tgt_bf = (unsigned short*)(ws + featB);
    float* e1 = (float*)(ws + 2 * featB);
    float* e2 = e1 + N_PTS;
    float* ap = e2 + N_PTS;
    float* an = ap + N_PTS;

    prep_kernel<<<N_PTS / 4, 256, 0, stream>>>(src, tgt, src_bf, tgt_bf,
                                               e1, e2, ap, an);
    dim3 grid(N_PTS / BN, N_PTS / BM);
    dist_kernel<<<grid, 256, 0, stream>>>(src_bf, tgt_bf, e1, e2, labels,
                                          ap, an);
    loss_kernel<<<1, 256, 0, stream>>>(ap, an, (float*)d_out);
}

// Round 7
// 106.974 us; speedup vs baseline: 1.3234x; 1.0456x over previous
//
#include <hip/hip_runtime.h>
#include <hip/hip_bf16.h>
#include <stdint.h>

#define N_PTS 4096
#define DIM 512
#define MARGIN_F 0.3f
#define POS_INF_BITS 0x7f800000

typedef short bf16x8 __attribute__((ext_vector_type(8)));
typedef float f32x4 __attribute__((ext_vector_type(4)));

__device__ __forceinline__ unsigned short f2bf(float f) {
    unsigned int b = __float_as_uint(f);
    b += 0x7FFF + ((b >> 16) & 1);   // round-to-nearest-even
    return (unsigned short)(b >> 16);
}

// async global->LDS, 16B per lane; LDS dest is wave-uniform base + lane*16
__device__ __forceinline__ void async16(const unsigned short* g, unsigned short* l) {
    __builtin_amdgcn_global_load_lds(
        (const __attribute__((address_space(1))) unsigned int*)g,
        (__attribute__((address_space(3))) unsigned int*)l,
        16, 0, 0);
}

// One wave per row: bf16 copy + exact fp32 norms; block 0 zeros the output accumulator.
__global__ __launch_bounds__(256) void prep_kernel(
    const float* __restrict__ src, const float* __restrict__ tgt,
    unsigned short* __restrict__ src_bf, unsigned short* __restrict__ tgt_bf,
    float* __restrict__ e1, float* __restrict__ e2,
    float* __restrict__ out)
{
    const int row  = blockIdx.x * 4 + (threadIdx.x >> 6);
    const int lane = threadIdx.x & 63;

    if (blockIdx.x == 0 && threadIdx.x == 0) out[0] = 0.0f;

    const float4* s4 = (const float4*)(src + (size_t)row * DIM);
    const float4* t4 = (const float4*)(tgt + (size_t)row * DIM);
    float4 a0 = s4[lane], a1 = s4[lane + 64];
    float4 b0 = t4[lane], b1 = t4[lane + 64];

    ushort4 u;
    ushort4* so = (ushort4*)(src_bf + (size_t)row * DIM);
    ushort4* to = (ushort4*)(tgt_bf + (size_t)row * DIM);
    u.x = f2bf(a0.x); u.y = f2bf(a0.y); u.z = f2bf(a0.z); u.w = f2bf(a0.w); so[lane] = u;
    u.x = f2bf(a1.x); u.y = f2bf(a1.y); u.z = f2bf(a1.z); u.w = f2bf(a1.w); so[lane + 64] = u;
    u.x = f2bf(b0.x); u.y = f2bf(b0.y); u.z = f2bf(b0.z); u.w = f2bf(b0.w); to[lane] = u;
    u.x = f2bf(b1.x); u.y = f2bf(b1.y); u.z = f2bf(b1.z); u.w = f2bf(b1.w); to[lane + 64] = u;

    float s1 = a0.x*a0.x + a0.y*a0.y + a0.z*a0.z + a0.w*a0.w
             + a1.x*a1.x + a1.y*a1.y + a1.z*a1.z + a1.w*a1.w;
    float s2 = b0.x*b0.x + b0.y*b0.y + b0.z*b0.z + b0.w*b0.w
             + b1.x*b1.x + b1.y*b1.y + b1.z*b1.z + b1.w*b1.w;
    for (int off = 32; off; off >>= 1) {
        s1 += __shfl_down(s1, off);
        s2 += __shfl_down(s2, off);
    }
    if (lane == 0) {
        e1[row] = s1;
        e2[row] = s2;
    }
}

#define BM 128
#define BN 128
#define BK 32
#define NPART 64   // 32 col-blocks x 2 col-waves -> 64 partials per row

__global__ __launch_bounds__(256) void dist_kernel(
    const unsigned short* __restrict__ src_bf,
    const unsigned short* __restrict__ tgt_bf,
    const float* __restrict__ e1, const float* __restrict__ e2,
    const int* __restrict__ labels,
    float* __restrict__ ap_part, float* __restrict__ an_part)
{
    // [128][32] bf16, XOR-swizzled at 16B-chunk granularity (measured:
    // SQ_LDS_BANK_CONFLICT == 0). Swizzle applied on the GLOBAL source
    // address; global_load_lds LDS dest is fixed base+lane*16.
    // Round-4 lesson: no device-scope fences here (L2 writeback evicts panels).
    // Round-6 lesson: no atomics to shared output rows (L2-slice serialization);
    // plain per-(row, col-wave) partial stores — round-6 bug was two waves
    // sharing one partial slot; fixed by indexing with (blockIdx.x*2 + wave&1).
    __shared__ unsigned short As[BM * BK];
    __shared__ unsigned short Bs[BN * BK];
    __shared__ int   li[BM];
    __shared__ int   lj[BN];
    __shared__ float e1s[BM];
    __shared__ float e2s[BN];

    const int i0 = blockIdx.y * BM;
    const int j0 = blockIdx.x * BN;
    const int t = threadIdx.x;
    const int lane = t & 63;
    const int wave = t >> 6;

    if (t < BM) { li[t] = labels[i0 + t]; e1s[t] = e1[i0 + t]; }
    else        { int u = t - BM; lj[u] = labels[j0 + u]; e2s[u] = e2[j0 + u]; }

    // staging: 512 16B-chunks per matrix per K-tile; thread t covers chunks
    // t (rows 0..63) and t+256 (rows 64..127). Physical chunk col = t&3 holds
    // logical chunk (t&3) ^ ((row>>1)&3); key identical for row and row+64.
    const int srow = t >> 2;                              // 0..63
    const int scol = ((t & 3) ^ ((srow >> 1) & 3)) * 8;   // swizzled source col
    const unsigned short* gA0 = src_bf + (size_t)(i0 + srow) * DIM + scol;
    const unsigned short* gA1 = src_bf + (size_t)(i0 + 64 + srow) * DIM + scol;
    const unsigned short* gB0 = tgt_bf + (size_t)(j0 + srow) * DIM + scol;
    const unsigned short* gB1 = tgt_bf + (size_t)(j0 + 64 + srow) * DIM + scol;
    unsigned short* ldsA0 = &As[0] + wave * 512;          // chunk base wave*64
    unsigned short* ldsA1 = &As[0] + 2048 + wave * 512;   // chunk base 256+wave*64
    unsigned short* ldsB0 = &Bs[0] + wave * 512;
    unsigned short* ldsB1 = &Bs[0] + 2048 + wave * 512;

    // wave -> 64x64 subtile: 4x4 of 16x16x32 MFMA
    const int wm = (wave >> 1) * 64;
    const int wn = (wave & 1) * 64;
    const int fr = lane & 15;
    const int quad = lane >> 4;
    const int fkey = (fr >> 1) & 3;                       // read-side XOR key

    f32x4 acc[4][4];
    #pragma unroll
    for (int a = 0; a < 4; a++)
        #pragma unroll
        for (int b = 0; b < 4; b++)
            acc[a][b] = (f32x4){0.f, 0.f, 0.f, 0.f};

    for (int kk = 0; kk < DIM; kk += BK) {
        __syncthreads();
        async16(gA0 + kk, ldsA0);
        async16(gA1 + kk, ldsA1);
        async16(gB0 + kk, ldsB0);
        async16(gB1 + kk, ldsB1);
        __syncthreads();   // vmcnt(0) drain inserted by compiler

        bf16x8 af[4], bf[4];
        const int cp = (quad ^ fkey) * 8;                 // physical chunk off
        #pragma unroll
        for (int x = 0; x < 4; x++) {
            af[x] = *(const bf16x8*)&As[(wm + x * 16 + fr) * BK + cp];
            bf[x] = *(const bf16x8*)&Bs[(wn + x * 16 + fr) * BK + cp];
        }
        #pragma unroll
        for (int tm = 0; tm < 4; tm++)
            #pragma unroll
            for (int tn = 0; tn < 4; tn++)
                acc[tm][tn] = __builtin_amdgcn_mfma_f32_16x16x32_bf16(
                    af[tm], bf[tn], acc[tm][tn], 0, 0, 0);
    }

    // epilogue: dist -> masked row max/min -> 16-lane reduce -> partial store
    const float INF = __int_as_float(POS_INF_BITS);
    const int pcol = blockIdx.x * 2 + (wave & 1);        // per-col-wave slot
    #pragma unroll
    for (int tm = 0; tm < 4; tm++) {
        #pragma unroll
        for (int r = 0; r < 4; r++) {
            const int rl = wm + tm * 16 + quad * 4 + r;  // local row
            const float e1v = e1s[rl];
            const int   liv = li[rl];
            float apv = 0.0f;   // neutral for max (dist >= 0)
            float anv = INF;
            #pragma unroll
            for (int tn = 0; tn < 4; tn++) {
                const int cl = wn + tn * 16 + fr;        // local col
                float d = e1v + e2s[cl] - 2.0f * acc[tm][tn][r];
                d = fmaxf(d, 0.0f);
                if (liv == lj[cl]) apv = fmaxf(apv, d);
                else               anv = fminf(anv, d);
            }
            #pragma unroll
            for (int off = 1; off < 16; off <<= 1) {
                apv = fmaxf(apv, __shfl_xor(apv, off));
                anv = fminf(anv, __shfl_xor(anv, off));
            }
            if (fr == 0) {
                ap_part[(size_t)(i0 + rl) * NPART + pcol] = apv;
                an_part[(size_t)(i0 + rl) * NPART + pcol] = anv;
            }
        }
    }
}

// 32 blocks x 128 threads; thread = one row: reduce 64 partials, relu, sum.
__global__ __launch_bounds__(128) void loss_kernel(
    const float* __restrict__ ap_part, const float* __restrict__ an_part,
    float* __restrict__ out)
{
    const int row = blockIdx.x * 128 + threadIdx.x;
    const float4* a4 = (const float4*)(ap_part + (size_t)row * NPART);
    const float4* n4 = (const float4*)(an_part + (size_t)row * NPART);
    float apv = 0.0f;
    float anv = __int_as_float(POS_INF_BITS);
    #pragma unroll
    for (int i = 0; i < NPART / 4; i++) {
        float4 a = a4[i], n = n4[i];
        apv = fmaxf(apv, fmaxf(fmaxf(a.x, a.y), fmaxf(a.z, a.w)));
        anv = fminf(anv, fminf(fminf(n.x, n.y), fminf(n.z, n.w)));
    }
    float s = fmaxf(apv - anv + MARGIN_F, 0.0f);
    for (int off = 32; off; off >>= 1) s += __shfl_down(s, off);
    __shared__ float red[2];
    if ((threadIdx.x & 63) == 0) red[threadIdx.x >> 6] = s;
    __syncthreads();
    if (threadIdx.x == 0)
        atomicAdd(out, (red[0] + red[1]) / (float)N_PTS);
}

extern "C" void kernel_launch(void* const* d_in, const int* in_sizes, int n_in,
                              void* d_out, int out_size, void* d_ws, size_t ws_size,
                              hipStream_t stream) {
    const float* src   = (const float*)d_in[0];
    const float* tgt   = (const float*)d_in[1];
    const int* labels  = (const int*)d_in[2];

    char* ws = (char*)d_ws;
    const size_t featB = (size_t)N_PTS * DIM * sizeof(unsigned short);  // 4 MiB
    unsigned short* src_bf = (unsigned short*)ws;
    unsigned short* tgt_bf = (unsigned short*)(ws + featB);
    float* e1 = (float*)(ws + 2 * featB);
    float* e2 = e1 + N_PTS;
    float* ap_part = e2 + N_PTS;                 // [N_PTS][NPART] = 1 MiB
    float* an_part = ap_part + (size_t)N_PTS * NPART;

    prep_kernel<<<N_PTS / 4, 256, 0, stream>>>(src, tgt, src_bf, tgt_bf,
                                               e1, e2, (float*)d_out);
    dim3 grid(N_PTS / BN, N_PTS / BM);
    dist_kernel<<<grid, 256, 0, stream>>>(src_bf, tgt_bf, e1, e2, labels,
                                          ap_part, an_part);
    loss_kernel<<<N_PTS / 128, 128, 0, stream>>>(ap_part, an_part, (float*)d_out);
}